// Round 4
// baseline (207.873 us; speedup 1.0000x reference)
//
#include <hip/hip_runtime.h>

// MultiVectorFieldModel: per-point routed tiny MLP (17 -> 6 -> 16), 65 models.
// Weights stored in LDS as RTN-rounded bf16 pairs, model-minor, padded to
// float4-chunk section boundaries:
//   chunks 0..12  : W1  (102 w, flat i*6+j, 2 pad)
//   chunk  13     : b1  (6 w, 2 pad)
//   chunks 14..25 : W2  (96 w, flat j*16+d)  -> row j = chunks 14+2j, 15+2j
//   chunks 26..27 : b2  (16 w)
// 28 chunks x 65 models x 16B = 29120 B LDS -> 4 blocks/CU at BLOCK=512
// -> 32 waves/CU. Gather: 28 x ds_read_b128, base mid*16, chunk index folds
// into offset: immediate (max 27*1040 = 28080 < 65536).

#define NMODELS 65
#define NCHUNK 28
#define BLOCK 512

__device__ inline unsigned f2bf(float f) {
    unsigned u = __builtin_bit_cast(unsigned, f);
    u += 0x7fffu + ((u >> 16) & 1u);   // round-to-nearest-even
    return u >> 16;
}
__device__ inline float bflo(unsigned v) { return __builtin_bit_cast(float, v << 16); }
__device__ inline float bfhi(unsigned v) { return __builtin_bit_cast(float, v & 0xffff0000u); }

__global__ __launch_bounds__(BLOCK, 8) void mvf_kernel(
    const float* __restrict__ x,
    const float* __restrict__ W1,
    const float* __restrict__ b1,
    const float* __restrict__ W2,
    const float* __restrict__ b2,
    float* __restrict__ out,
    int npts)
{
    __shared__ unsigned wlds[NCHUNK * NMODELS * 4];   // 29120 B
    const int tid = threadIdx.x;

    // ---- stage weights: fp32 -> bf16 pair per u32, model-minor ----
    for (int e = tid; e < NMODELS * NCHUNK * 4; e += BLOCK) {
        const int m = e / (NCHUNK * 4);
        const int idx = e - m * (NCHUNK * 4);
        const int c = idx >> 2, s = idx & 3;
        float2 v = make_float2(0.0f, 0.0f);
        if (c < 13) {
            const int p2 = c * 4 + s;                 // W1 pair
            if (p2 < 51) v = *(const float2*)(W1 + m * 102 + 2 * p2);
        } else if (c == 13) {
            if (s < 3) v = *(const float2*)(b1 + m * 6 + 2 * s);
        } else if (c < 26) {
            const int q = (c - 14) * 4 + s;           // W2 pair
            v = *(const float2*)(W2 + m * 96 + 2 * q);
        } else {
            const int r = (c - 26) * 4 + s;           // b2 pair
            v = *(const float2*)(b2 + m * 16 + 2 * r);
        }
        wlds[c * (NMODELS * 4) + m * 4 + s] = f2bf(v.x) | (f2bf(v.y) << 16);
    }
    __syncthreads();

    const int p = blockIdx.x * BLOCK + tid;
    if (p >= npts) return;

    // ---- load x row: 18 floats, rows are 72B (8B-aligned) ----
    float xf[18];
    const float2* xr = (const float2*)(x + (long)p * 18);
    #pragma unroll
    for (int i = 0; i < 9; ++i) {
        float2 v = xr[i];
        xf[2 * i]     = v.x;
        xf[2 * i + 1] = v.y;
    }
    const float t = xf[17];
    const int c = (int)xf[16];
    int bucket = (int)floorf(t * 8.0f);
    bucket = bucket < 0 ? 0 : (bucket > 7 ? 7 : bucket);
    const int mid = (c == 0) ? 0 : 1 + (c - 1) * 8 + bucket;

    const uint4* wl4 = (const uint4*)wlds;
    #define CH(cc) wl4[(cc) * NMODELS + mid]

    // ---- h = relu(xin @ W1 + b1), xin = [data[0..15], t] ----
    float h[6];
    {
        uint4 cb = CH(13);
        h[0] = bflo(cb.x); h[1] = bfhi(cb.x);
        h[2] = bflo(cb.y); h[3] = bfhi(cb.y);
        h[4] = bflo(cb.z); h[5] = bfhi(cb.z);
    }
    #pragma unroll
    for (int g = 0; g < 4; ++g) {
        uint4 a  = CH(3 * g + 0);
        uint4 b  = CH(3 * g + 1);
        uint4 c2 = CH(3 * g + 2);
        const float x0 = xf[4 * g + 0], x1 = xf[4 * g + 1];
        const float x2 = xf[4 * g + 2], x3 = xf[4 * g + 3];
        h[0] = fmaf(x0, bflo(a.x), h[0]);  h[1] = fmaf(x0, bfhi(a.x), h[1]);
        h[2] = fmaf(x0, bflo(a.y), h[2]);  h[3] = fmaf(x0, bfhi(a.y), h[3]);
        h[4] = fmaf(x0, bflo(a.z), h[4]);  h[5] = fmaf(x0, bfhi(a.z), h[5]);
        h[0] = fmaf(x1, bflo(a.w), h[0]);  h[1] = fmaf(x1, bfhi(a.w), h[1]);
        h[2] = fmaf(x1, bflo(b.x), h[2]);  h[3] = fmaf(x1, bfhi(b.x), h[3]);
        h[4] = fmaf(x1, bflo(b.y), h[4]);  h[5] = fmaf(x1, bfhi(b.y), h[5]);
        h[0] = fmaf(x2, bflo(b.z), h[0]);  h[1] = fmaf(x2, bfhi(b.z), h[1]);
        h[2] = fmaf(x2, bflo(b.w), h[2]);  h[3] = fmaf(x2, bfhi(b.w), h[3]);
        h[4] = fmaf(x2, bflo(c2.x), h[4]); h[5] = fmaf(x2, bfhi(c2.x), h[5]);
        h[0] = fmaf(x3, bflo(c2.y), h[0]); h[1] = fmaf(x3, bfhi(c2.y), h[1]);
        h[2] = fmaf(x3, bflo(c2.z), h[2]); h[3] = fmaf(x3, bfhi(c2.z), h[3]);
        h[4] = fmaf(x3, bflo(c2.w), h[4]); h[5] = fmaf(x3, bfhi(c2.w), h[5]);
    }
    {
        uint4 ct = CH(12);   // W1 row 16 (the t row), weights 96..101
        h[0] = fmaf(t, bflo(ct.x), h[0]); h[1] = fmaf(t, bfhi(ct.x), h[1]);
        h[2] = fmaf(t, bflo(ct.y), h[2]); h[3] = fmaf(t, bfhi(ct.y), h[3]);
        h[4] = fmaf(t, bflo(ct.z), h[4]); h[5] = fmaf(t, bfhi(ct.z), h[5]);
    }
    #pragma unroll
    for (int j = 0; j < 6; ++j) h[j] = h[j] > 0.0f ? h[j] : 0.0f;

    // ---- out = h @ W2 + b2 ----
    float o[16];
    {
        uint4 ba = CH(26), bb = CH(27);
        o[0]  = bflo(ba.x); o[1]  = bfhi(ba.x); o[2]  = bflo(ba.y); o[3]  = bfhi(ba.y);
        o[4]  = bflo(ba.z); o[5]  = bfhi(ba.z); o[6]  = bflo(ba.w); o[7]  = bfhi(ba.w);
        o[8]  = bflo(bb.x); o[9]  = bfhi(bb.x); o[10] = bflo(bb.y); o[11] = bfhi(bb.y);
        o[12] = bflo(bb.z); o[13] = bfhi(bb.z); o[14] = bflo(bb.w); o[15] = bfhi(bb.w);
    }
    #pragma unroll
    for (int j = 0; j < 6; ++j) {
        uint4 A = CH(14 + 2 * j);
        uint4 B = CH(15 + 2 * j);
        const float hj = h[j];
        o[0]  = fmaf(hj, bflo(A.x), o[0]);  o[1]  = fmaf(hj, bfhi(A.x), o[1]);
        o[2]  = fmaf(hj, bflo(A.y), o[2]);  o[3]  = fmaf(hj, bfhi(A.y), o[3]);
        o[4]  = fmaf(hj, bflo(A.z), o[4]);  o[5]  = fmaf(hj, bfhi(A.z), o[5]);
        o[6]  = fmaf(hj, bflo(A.w), o[6]);  o[7]  = fmaf(hj, bfhi(A.w), o[7]);
        o[8]  = fmaf(hj, bflo(B.x), o[8]);  o[9]  = fmaf(hj, bfhi(B.x), o[9]);
        o[10] = fmaf(hj, bflo(B.y), o[10]); o[11] = fmaf(hj, bfhi(B.y), o[11]);
        o[12] = fmaf(hj, bflo(B.z), o[12]); o[13] = fmaf(hj, bfhi(B.z), o[13]);
        o[14] = fmaf(hj, bflo(B.w), o[14]); o[15] = fmaf(hj, bfhi(B.w), o[15]);
    }
    #undef CH

    // ---- store: 16 floats = 4 x float4, 64B rows (aligned) ----
    float4* orow = (float4*)(out + (long)p * 16);
    #pragma unroll
    for (int q = 0; q < 4; ++q) {
        orow[q] = make_float4(o[4 * q], o[4 * q + 1], o[4 * q + 2], o[4 * q + 3]);
    }
}

extern "C" void kernel_launch(void* const* d_in, const int* in_sizes, int n_in,
                              void* d_out, int out_size, void* d_ws, size_t ws_size,
                              hipStream_t stream) {
    const float* x  = (const float*)d_in[0];
    const float* W1 = (const float*)d_in[1];
    const float* b1 = (const float*)d_in[2];
    const float* W2 = (const float*)d_in[3];
    const float* b2 = (const float*)d_in[4];
    float* out = (float*)d_out;

    const int npts = in_sizes[0] / 18;
    const int grid = (npts + BLOCK - 1) / BLOCK;
    mvf_kernel<<<grid, BLOCK, 0, stream>>>(x, W1, b1, W2, b2, out, npts);
}

// Round 5
// 73.534 us; speedup vs baseline: 2.8269x; 2.8269x over previous
//
#include <hip/hip_runtime.h>

// MultiVectorFieldModel: per-point routed tiny MLP (17 -> 6 -> 16), 65 models.
// Weights in LDS as RTN-rounded bf16 pairs, model-minor, float4 chunks:
//   chunks 0..12  : W1  (102 w, flat i*6+j, 2 pad)
//   chunk  13     : b1  (6 w, 2 pad)
//   chunks 14..25 : W2  (96 w, flat j*16+d)  -> row j = chunks 14+2j, 15+2j
//   chunks 26..27 : b2  (16 w)
// 28 chunks x 65 models x 16B = 29120 B LDS. Gather: 28 x ds_read_b128,
// base mid*16, chunk index folds into offset: immediate.
//
// R3 lesson: __launch_bounds__(512,8) (VGPR cap 64) caused a full scratch
// spill (FETCH 290MB / WRITE 529MB). Use min-waves=4 (cap 128) and keep
// liveness low by interleaving x loads with their FMA groups.

#define NMODELS 65
#define NCHUNK 28
#define BLOCK 512

__device__ inline unsigned f2bf(float f) {
    unsigned u = __builtin_bit_cast(unsigned, f);
    u += 0x7fffu + ((u >> 16) & 1u);   // round-to-nearest-even
    return u >> 16;
}
__device__ inline float bflo(unsigned v) { return __builtin_bit_cast(float, v << 16); }
__device__ inline float bfhi(unsigned v) { return __builtin_bit_cast(float, v & 0xffff0000u); }

__global__ __launch_bounds__(BLOCK, 4) void mvf_kernel(
    const float* __restrict__ x,
    const float* __restrict__ W1,
    const float* __restrict__ b1,
    const float* __restrict__ W2,
    const float* __restrict__ b2,
    float* __restrict__ out,
    int npts)
{
    __shared__ unsigned wlds[NCHUNK * NMODELS * 4];   // 29120 B
    const int tid = threadIdx.x;

    // ---- stage weights: fp32 -> bf16 pair per u32, model-minor ----
    for (int e = tid; e < NMODELS * NCHUNK * 4; e += BLOCK) {
        const int m = e / (NCHUNK * 4);
        const int idx = e - m * (NCHUNK * 4);
        const int c = idx >> 2, s = idx & 3;
        float2 v = make_float2(0.0f, 0.0f);
        if (c < 13) {
            const int p2 = c * 4 + s;                 // W1 pair
            if (p2 < 51) v = *(const float2*)(W1 + m * 102 + 2 * p2);
        } else if (c == 13) {
            if (s < 3) v = *(const float2*)(b1 + m * 6 + 2 * s);
        } else if (c < 26) {
            const int q = (c - 14) * 4 + s;           // W2 pair
            v = *(const float2*)(W2 + m * 96 + 2 * q);
        } else {
            const int r = (c - 26) * 4 + s;           // b2 pair
            v = *(const float2*)(b2 + m * 16 + 2 * r);
        }
        wlds[c * (NMODELS * 4) + m * 4 + s] = f2bf(v.x) | (f2bf(v.y) << 16);
    }
    __syncthreads();

    const int p = blockIdx.x * BLOCK + tid;
    if (p >= npts) return;

    const float2* xr = (const float2*)(x + (long)p * 18);

    // ---- routing first so the LDS gather address is ready early ----
    const float2 xct = xr[8];           // (cond, t)
    const float t = xct.y;
    const int c = (int)xct.x;
    int bucket = (int)floorf(t * 8.0f);
    bucket = bucket < 0 ? 0 : (bucket > 7 ? 7 : bucket);
    const int mid = (c == 0) ? 0 : 1 + (c - 1) * 8 + bucket;

    const uint4* wl4 = (const uint4*)wlds;
    #define CH(cc) wl4[(cc) * NMODELS + mid]

    // ---- h = relu(xin @ W1 + b1), xin = [data[0..15], t] ----
    float h[6];
    {
        uint4 cb = CH(13);
        h[0] = bflo(cb.x); h[1] = bfhi(cb.x);
        h[2] = bflo(cb.y); h[3] = bfhi(cb.y);
        h[4] = bflo(cb.z); h[5] = bfhi(cb.z);
    }
    {
        uint4 ct = CH(12);   // W1 row 16 (the t row), weights 96..101
        h[0] = fmaf(t, bflo(ct.x), h[0]); h[1] = fmaf(t, bfhi(ct.x), h[1]);
        h[2] = fmaf(t, bflo(ct.y), h[2]); h[3] = fmaf(t, bfhi(ct.y), h[3]);
        h[4] = fmaf(t, bflo(ct.z), h[4]); h[5] = fmaf(t, bfhi(ct.z), h[5]);
    }
    #pragma unroll
    for (int g = 0; g < 4; ++g) {
        // x pairs loaded inside the group to bound liveness
        const float2 xa = xr[2 * g + 0];
        const float2 xb = xr[2 * g + 1];
        uint4 a  = CH(3 * g + 0);
        uint4 b  = CH(3 * g + 1);
        uint4 c2 = CH(3 * g + 2);
        const float x0 = xa.x, x1 = xa.y, x2 = xb.x, x3 = xb.y;
        h[0] = fmaf(x0, bflo(a.x), h[0]);  h[1] = fmaf(x0, bfhi(a.x), h[1]);
        h[2] = fmaf(x0, bflo(a.y), h[2]);  h[3] = fmaf(x0, bfhi(a.y), h[3]);
        h[4] = fmaf(x0, bflo(a.z), h[4]);  h[5] = fmaf(x0, bfhi(a.z), h[5]);
        h[0] = fmaf(x1, bflo(a.w), h[0]);  h[1] = fmaf(x1, bfhi(a.w), h[1]);
        h[2] = fmaf(x1, bflo(b.x), h[2]);  h[3] = fmaf(x1, bfhi(b.x), h[3]);
        h[4] = fmaf(x1, bflo(b.y), h[4]);  h[5] = fmaf(x1, bfhi(b.y), h[5]);
        h[0] = fmaf(x2, bflo(b.z), h[0]);  h[1] = fmaf(x2, bfhi(b.z), h[1]);
        h[2] = fmaf(x2, bflo(b.w), h[2]);  h[3] = fmaf(x2, bfhi(b.w), h[3]);
        h[4] = fmaf(x2, bflo(c2.x), h[4]); h[5] = fmaf(x2, bfhi(c2.x), h[5]);
        h[0] = fmaf(x3, bflo(c2.y), h[0]); h[1] = fmaf(x3, bfhi(c2.y), h[1]);
        h[2] = fmaf(x3, bflo(c2.z), h[2]); h[3] = fmaf(x3, bfhi(c2.z), h[3]);
        h[4] = fmaf(x3, bflo(c2.w), h[4]); h[5] = fmaf(x3, bfhi(c2.w), h[5]);
    }
    #pragma unroll
    for (int j = 0; j < 6; ++j) h[j] = h[j] > 0.0f ? h[j] : 0.0f;

    // ---- out = h @ W2 + b2 ----
    float o[16];
    {
        uint4 ba = CH(26), bb = CH(27);
        o[0]  = bflo(ba.x); o[1]  = bfhi(ba.x); o[2]  = bflo(ba.y); o[3]  = bfhi(ba.y);
        o[4]  = bflo(ba.z); o[5]  = bfhi(ba.z); o[6]  = bflo(ba.w); o[7]  = bfhi(ba.w);
        o[8]  = bflo(bb.x); o[9]  = bfhi(bb.x); o[10] = bflo(bb.y); o[11] = bfhi(bb.y);
        o[12] = bflo(bb.z); o[13] = bfhi(bb.z); o[14] = bflo(bb.w); o[15] = bfhi(bb.w);
    }
    #pragma unroll
    for (int j = 0; j < 6; ++j) {
        uint4 A = CH(14 + 2 * j);
        uint4 B = CH(15 + 2 * j);
        const float hj = h[j];
        o[0]  = fmaf(hj, bflo(A.x), o[0]);  o[1]  = fmaf(hj, bfhi(A.x), o[1]);
        o[2]  = fmaf(hj, bflo(A.y), o[2]);  o[3]  = fmaf(hj, bfhi(A.y), o[3]);
        o[4]  = fmaf(hj, bflo(A.z), o[4]);  o[5]  = fmaf(hj, bfhi(A.z), o[5]);
        o[6]  = fmaf(hj, bflo(A.w), o[6]);  o[7]  = fmaf(hj, bfhi(A.w), o[7]);
        o[8]  = fmaf(hj, bflo(B.x), o[8]);  o[9]  = fmaf(hj, bfhi(B.x), o[9]);
        o[10] = fmaf(hj, bflo(B.y), o[10]); o[11] = fmaf(hj, bfhi(B.y), o[11]);
        o[12] = fmaf(hj, bflo(B.z), o[12]); o[13] = fmaf(hj, bfhi(B.z), o[13]);
        o[14] = fmaf(hj, bflo(B.w), o[14]); o[15] = fmaf(hj, bfhi(B.w), o[15]);
    }
    #undef CH

    // ---- store: 16 floats = 4 x float4, 64B rows (aligned) ----
    float4* orow = (float4*)(out + (long)p * 16);
    #pragma unroll
    for (int q = 0; q < 4; ++q) {
        orow[q] = make_float4(o[4 * q], o[4 * q + 1], o[4 * q + 2], o[4 * q + 3]);
    }
}

extern "C" void kernel_launch(void* const* d_in, const int* in_sizes, int n_in,
                              void* d_out, int out_size, void* d_ws, size_t ws_size,
                              hipStream_t stream) {
    const float* x  = (const float*)d_in[0];
    const float* W1 = (const float*)d_in[1];
    const float* b1 = (const float*)d_in[2];
    const float* W2 = (const float*)d_in[3];
    const float* b2 = (const float*)d_in[4];
    float* out = (float*)d_out;

    const int npts = in_sizes[0] / 18;
    const int grid = (npts + BLOCK - 1) / BLOCK;
    mvf_kernel<<<grid, BLOCK, 0, stream>>>(x, W1, b1, W2, b2, out, npts);
}

// Round 6
// 60.511 us; speedup vs baseline: 3.4353x; 1.2152x over previous
//
#include <hip/hip_runtime.h>

// MultiVectorFieldModel: per-point routed tiny MLP (17 -> 6 -> 16), 65 models.
// Weights in LDS as RTN-rounded bf16 pairs, model-minor, float4 chunks:
//   chunks 0..12  : W1  (102 w, flat i*6+j, 2 pad)
//   chunk  13     : b1  (6 w, 2 pad)
//   chunks 14..25 : W2  (96 w, flat j*16+d)  -> row j = chunks 14+2j, 15+2j
//   chunks 26..27 : b2  (16 w)
// 28 chunks x 65 models x 16B = 29120 B LDS. Gather: 28 x ds_read_b128,
// base mid*16, chunk index folds into offset: immediate.
//
// R3 lesson: tight VGPR caps (cap=64) trigger catastrophic scratch spill.
// R4 lesson: interleaving x loads with FMA groups serializes the chain
// (each group waits ~900cy HBM); BLOCK=512 halves waves/CU. This round:
// BLOCK=1024 (2 blocks/CU = 32 waves/CU), all 9 x float2 loads upfront
// (single waitcnt), natural VGPR (cap 128, expect ~64).

#define NMODELS 65
#define NCHUNK 28
#define BLOCK 1024

__device__ inline unsigned f2bf(float f) {
    unsigned u = __builtin_bit_cast(unsigned, f);
    u += 0x7fffu + ((u >> 16) & 1u);   // round-to-nearest-even
    return u >> 16;
}
__device__ inline float bflo(unsigned v) { return __builtin_bit_cast(float, v << 16); }
__device__ inline float bfhi(unsigned v) { return __builtin_bit_cast(float, v & 0xffff0000u); }

__global__ __launch_bounds__(BLOCK, 4) void mvf_kernel(
    const float* __restrict__ x,
    const float* __restrict__ W1,
    const float* __restrict__ b1,
    const float* __restrict__ W2,
    const float* __restrict__ b2,
    float* __restrict__ out,
    int npts)
{
    __shared__ unsigned wlds[NCHUNK * NMODELS * 4];   // 29120 B
    const int tid = threadIdx.x;

    // ---- stage weights: fp32 -> bf16 pair per u32, model-minor ----
    for (int e = tid; e < NMODELS * NCHUNK * 4; e += BLOCK) {
        const int m = e / (NCHUNK * 4);
        const int idx = e - m * (NCHUNK * 4);
        const int c = idx >> 2, s = idx & 3;
        float2 v = make_float2(0.0f, 0.0f);
        if (c < 13) {
            const int p2 = c * 4 + s;                 // W1 pair
            if (p2 < 51) v = *(const float2*)(W1 + m * 102 + 2 * p2);
        } else if (c == 13) {
            if (s < 3) v = *(const float2*)(b1 + m * 6 + 2 * s);
        } else if (c < 26) {
            const int q = (c - 14) * 4 + s;           // W2 pair
            v = *(const float2*)(W2 + m * 96 + 2 * q);
        } else {
            const int r = (c - 26) * 4 + s;           // b2 pair
            v = *(const float2*)(b2 + m * 16 + 2 * r);
        }
        wlds[c * (NMODELS * 4) + m * 4 + s] = f2bf(v.x) | (f2bf(v.y) << 16);
    }
    __syncthreads();

    const int p = blockIdx.x * BLOCK + tid;
    if (p >= npts) return;

    // ---- load x row upfront: 9 independent float2 loads, one wait ----
    const float2* xr = (const float2*)(x + (long)p * 18);
    float xf[18];
    #pragma unroll
    for (int i = 0; i < 9; ++i) {
        float2 v = xr[i];
        xf[2 * i]     = v.x;
        xf[2 * i + 1] = v.y;
    }

    const float t = xf[17];
    const int c = (int)xf[16];
    int bucket = (int)floorf(t * 8.0f);
    bucket = bucket < 0 ? 0 : (bucket > 7 ? 7 : bucket);
    const int mid = (c == 0) ? 0 : 1 + (c - 1) * 8 + bucket;

    const uint4* wl4 = (const uint4*)wlds;
    #define CH(cc) wl4[(cc) * NMODELS + mid]

    // ---- h = relu(xin @ W1 + b1), xin = [data[0..15], t] ----
    float h[6];
    {
        uint4 cb = CH(13);
        h[0] = bflo(cb.x); h[1] = bfhi(cb.x);
        h[2] = bflo(cb.y); h[3] = bfhi(cb.y);
        h[4] = bflo(cb.z); h[5] = bfhi(cb.z);
    }
    {
        uint4 ct = CH(12);   // W1 row 16 (the t row), weights 96..101
        h[0] = fmaf(t, bflo(ct.x), h[0]); h[1] = fmaf(t, bfhi(ct.x), h[1]);
        h[2] = fmaf(t, bflo(ct.y), h[2]); h[3] = fmaf(t, bfhi(ct.y), h[3]);
        h[4] = fmaf(t, bflo(ct.z), h[4]); h[5] = fmaf(t, bfhi(ct.z), h[5]);
    }
    #pragma unroll
    for (int g = 0; g < 4; ++g) {
        uint4 a  = CH(3 * g + 0);
        uint4 b  = CH(3 * g + 1);
        uint4 c2 = CH(3 * g + 2);
        const float x0 = xf[4 * g + 0], x1 = xf[4 * g + 1];
        const float x2 = xf[4 * g + 2], x3 = xf[4 * g + 3];
        h[0] = fmaf(x0, bflo(a.x), h[0]);  h[1] = fmaf(x0, bfhi(a.x), h[1]);
        h[2] = fmaf(x0, bflo(a.y), h[2]);  h[3] = fmaf(x0, bfhi(a.y), h[3]);
        h[4] = fmaf(x0, bflo(a.z), h[4]);  h[5] = fmaf(x0, bfhi(a.z), h[5]);
        h[0] = fmaf(x1, bflo(a.w), h[0]);  h[1] = fmaf(x1, bfhi(a.w), h[1]);
        h[2] = fmaf(x1, bflo(b.x), h[2]);  h[3] = fmaf(x1, bfhi(b.x), h[3]);
        h[4] = fmaf(x1, bflo(b.y), h[4]);  h[5] = fmaf(x1, bfhi(b.y), h[5]);
        h[0] = fmaf(x2, bflo(b.z), h[0]);  h[1] = fmaf(x2, bfhi(b.z), h[1]);
        h[2] = fmaf(x2, bflo(b.w), h[2]);  h[3] = fmaf(x2, bfhi(b.w), h[3]);
        h[4] = fmaf(x2, bflo(c2.x), h[4]); h[5] = fmaf(x2, bfhi(c2.x), h[5]);
        h[0] = fmaf(x3, bflo(c2.y), h[0]); h[1] = fmaf(x3, bfhi(c2.y), h[1]);
        h[2] = fmaf(x3, bflo(c2.z), h[2]); h[3] = fmaf(x3, bfhi(c2.z), h[3]);
        h[4] = fmaf(x3, bflo(c2.w), h[4]); h[5] = fmaf(x3, bfhi(c2.w), h[5]);
    }
    #pragma unroll
    for (int j = 0; j < 6; ++j) h[j] = h[j] > 0.0f ? h[j] : 0.0f;

    // ---- out = h @ W2 + b2 ----
    float o[16];
    {
        uint4 ba = CH(26), bb = CH(27);
        o[0]  = bflo(ba.x); o[1]  = bfhi(ba.x); o[2]  = bflo(ba.y); o[3]  = bfhi(ba.y);
        o[4]  = bflo(ba.z); o[5]  = bfhi(ba.z); o[6]  = bflo(ba.w); o[7]  = bfhi(ba.w);
        o[8]  = bflo(bb.x); o[9]  = bfhi(bb.x); o[10] = bflo(bb.y); o[11] = bfhi(bb.y);
        o[12] = bflo(bb.z); o[13] = bfhi(bb.z); o[14] = bflo(bb.w); o[15] = bfhi(bb.w);
    }
    #pragma unroll
    for (int j = 0; j < 6; ++j) {
        uint4 A = CH(14 + 2 * j);
        uint4 B = CH(15 + 2 * j);
        const float hj = h[j];
        o[0]  = fmaf(hj, bflo(A.x), o[0]);  o[1]  = fmaf(hj, bfhi(A.x), o[1]);
        o[2]  = fmaf(hj, bflo(A.y), o[2]);  o[3]  = fmaf(hj, bfhi(A.y), o[3]);
        o[4]  = fmaf(hj, bflo(A.z), o[4]);  o[5]  = fmaf(hj, bfhi(A.z), o[5]);
        o[6]  = fmaf(hj, bflo(A.w), o[6]);  o[7]  = fmaf(hj, bfhi(A.w), o[7]);
        o[8]  = fmaf(hj, bflo(B.x), o[8]);  o[9]  = fmaf(hj, bfhi(B.x), o[9]);
        o[10] = fmaf(hj, bflo(B.y), o[10]); o[11] = fmaf(hj, bfhi(B.y), o[11]);
        o[12] = fmaf(hj, bflo(B.z), o[12]); o[13] = fmaf(hj, bfhi(B.z), o[13]);
        o[14] = fmaf(hj, bflo(B.w), o[14]); o[15] = fmaf(hj, bfhi(B.w), o[15]);
    }
    #undef CH

    // ---- store: 16 floats = 4 x float4, 64B rows (aligned) ----
    float4* orow = (float4*)(out + (long)p * 16);
    #pragma unroll
    for (int q = 0; q < 4; ++q) {
        orow[q] = make_float4(o[4 * q], o[4 * q + 1], o[4 * q + 2], o[4 * q + 3]);
    }
}

extern "C" void kernel_launch(void* const* d_in, const int* in_sizes, int n_in,
                              void* d_out, int out_size, void* d_ws, size_t ws_size,
                              hipStream_t stream) {
    const float* x  = (const float*)d_in[0];
    const float* W1 = (const float*)d_in[1];
    const float* b1 = (const float*)d_in[2];
    const float* W2 = (const float*)d_in[3];
    const float* b2 = (const float*)d_in[4];
    float* out = (float*)d_out;

    const int npts = in_sizes[0] / 18;
    const int grid = (npts + BLOCK - 1) / BLOCK;
    mvf_kernel<<<grid, BLOCK, 0, stream>>>(x, W1, b1, W2, b2, out, npts);
}

// Round 7
// 48.897 us; speedup vs baseline: 4.2512x; 1.2375x over previous
//
#include <hip/hip_runtime.h>

// MultiVectorFieldModel: per-point routed tiny MLP (17 -> 6 -> 16), 65 models.
// fp32 weights in LDS as float4 chunks, model-minor: wlds[k4][model], k4=0..54
// over the 220-float record {W1(102), b1(6), W2(96), b2(16)}:
//   chunks 0..23  : W1 rows 0..15 (3 chunks = 2 rows per group)
//   chunk  24     : W1 row 16 (t row) j0..3
//   chunk  25     : {W1[100], W1[101], b1[0], b1[1]}
//   chunk  26     : b1[2..5]
//   chunks 27..50 : W2 row j = chunks 27+4j .. 27+4j+3 (d-major)
//   chunks 51..54 : b2
// Gather: ds_read_b128 base mid*16, chunk folds into offset: immediate.
//
// R0-R5 lesson: duration ~invariant across LDS layouts/conflict counts ->
// latency-bound, one serial chain per wave. R6: 2 points/thread (even/odd
// pair -> float4 x loads), VGPR cap 128 (R3: cap 64 => catastrophic spill;
// check FETCH/WRITE stay at 36/62.5 MB), layer-2 in d-halves to cap liveness.

#define NMODELS 65
#define WPM 220
#define NCHUNK 55
#define BLOCK 512

__global__ __launch_bounds__(BLOCK, 4) void mvf_kernel(
    const float* __restrict__ x,
    const float* __restrict__ W1,
    const float* __restrict__ b1,
    const float* __restrict__ W2,
    const float* __restrict__ b2,
    float* __restrict__ out,
    int npts)
{
    __shared__ float4 wlds[NCHUNK][NMODELS];   // 55*65*16 = 57200 B
    const int tid = threadIdx.x;

    // ---- stage weights into LDS (scalar repack into float4 chunks) ----
    float* wf = (float*)wlds;
    for (int e = tid; e < NMODELS * WPM; e += BLOCK) {
        const int m = e / WPM, k = e % WPM;
        float v;
        if (k < 102)      v = W1[m * 102 + k];
        else if (k < 108) v = b1[m * 6 + (k - 102)];
        else if (k < 204) v = W2[m * 96 + (k - 108)];
        else              v = b2[m * 16 + (k - 204)];
        wf[(k >> 2) * (NMODELS * 4) + m * 4 + (k & 3)] = v;
    }
    __syncthreads();

    const int q = blockIdx.x * BLOCK + tid;   // pair index
    const int p0 = 2 * q;                     // points p0, p0+1
    if (p0 >= npts) return;

    // ---- load BOTH x rows upfront: 36 floats = 9 float4 (144B, aligned) ----
    float xf[36];
    {
        const float4* xr4 = (const float4*)(x + (long)p0 * 18);
        #pragma unroll
        for (int i = 0; i < 9; ++i) {
            float4 v = xr4[i];
            xf[4 * i + 0] = v.x;
            xf[4 * i + 1] = v.y;
            xf[4 * i + 2] = v.z;
            xf[4 * i + 3] = v.w;
        }
    }
    #define XF(pt, i) xf[(pt) * 18 + (i)]

    // ---- routing for both points ----
    int mid[2];
    float tt[2];
    #pragma unroll
    for (int pt = 0; pt < 2; ++pt) {
        const float t = XF(pt, 17);
        const int c = (int)XF(pt, 16);
        int bucket = (int)floorf(t * 8.0f);
        bucket = bucket < 0 ? 0 : (bucket > 7 ? 7 : bucket);
        mid[pt] = (c == 0) ? 0 : 1 + (c - 1) * 8 + bucket;
        tt[pt] = t;
    }

    #define CH(cc, pt) wlds[cc][mid[pt]]

    // ---- layer 1: h = relu(xin @ W1 + b1), xin = [data[0..15], t] ----
    float h[2][6];
    #pragma unroll
    for (int pt = 0; pt < 2; ++pt) {
        float4 c24 = CH(24, pt);
        float4 c25 = CH(25, pt);
        float4 c26 = CH(26, pt);
        const float t = tt[pt];
        h[pt][0] = fmaf(t, c24.x, c25.z);
        h[pt][1] = fmaf(t, c24.y, c25.w);
        h[pt][2] = fmaf(t, c24.z, c26.x);
        h[pt][3] = fmaf(t, c24.w, c26.y);
        h[pt][4] = fmaf(t, c25.x, c26.z);
        h[pt][5] = fmaf(t, c25.y, c26.w);
    }
    #pragma unroll
    for (int r = 0; r < 8; ++r) {
        #pragma unroll
        for (int pt = 0; pt < 2; ++pt) {
            float4 a = CH(3 * r + 0, pt);
            float4 b = CH(3 * r + 1, pt);
            float4 d = CH(3 * r + 2, pt);
            const float x0 = XF(pt, 2 * r), x1 = XF(pt, 2 * r + 1);
            h[pt][0] = fmaf(x0, a.x, h[pt][0]);
            h[pt][1] = fmaf(x0, a.y, h[pt][1]);
            h[pt][2] = fmaf(x0, a.z, h[pt][2]);
            h[pt][3] = fmaf(x0, a.w, h[pt][3]);
            h[pt][4] = fmaf(x0, b.x, h[pt][4]);
            h[pt][5] = fmaf(x0, b.y, h[pt][5]);
            h[pt][0] = fmaf(x1, b.z, h[pt][0]);
            h[pt][1] = fmaf(x1, b.w, h[pt][1]);
            h[pt][2] = fmaf(x1, d.x, h[pt][2]);
            h[pt][3] = fmaf(x1, d.y, h[pt][3]);
            h[pt][4] = fmaf(x1, d.z, h[pt][4]);
            h[pt][5] = fmaf(x1, d.w, h[pt][5]);
        }
    }
    #pragma unroll
    for (int pt = 0; pt < 2; ++pt)
        #pragma unroll
        for (int j = 0; j < 6; ++j)
            h[pt][j] = h[pt][j] > 0.0f ? h[pt][j] : 0.0f;

    // ---- layer 2 in d-halves: o[8] live at a time, store immediately ----
    #pragma unroll
    for (int half = 0; half < 2; ++half) {
        #pragma unroll
        for (int pt = 0; pt < 2; ++pt) {
            float o[8];
            {
                float4 ba = CH(51 + 2 * half, pt);
                float4 bb = CH(52 + 2 * half, pt);
                o[0] = ba.x; o[1] = ba.y; o[2] = ba.z; o[3] = ba.w;
                o[4] = bb.x; o[5] = bb.y; o[6] = bb.z; o[7] = bb.w;
            }
            #pragma unroll
            for (int j = 0; j < 6; ++j) {
                float4 A = CH(27 + 4 * j + 2 * half + 0, pt);
                float4 B = CH(27 + 4 * j + 2 * half + 1, pt);
                const float hj = h[pt][j];
                o[0] = fmaf(hj, A.x, o[0]);
                o[1] = fmaf(hj, A.y, o[1]);
                o[2] = fmaf(hj, A.z, o[2]);
                o[3] = fmaf(hj, A.w, o[3]);
                o[4] = fmaf(hj, B.x, o[4]);
                o[5] = fmaf(hj, B.y, o[5]);
                o[6] = fmaf(hj, B.z, o[6]);
                o[7] = fmaf(hj, B.w, o[7]);
            }
            float4* orow = (float4*)(out + (long)(p0 + pt) * 16 + half * 8);
            orow[0] = make_float4(o[0], o[1], o[2], o[3]);
            orow[1] = make_float4(o[4], o[5], o[6], o[7]);
        }
    }
    #undef CH
    #undef XF
}

extern "C" void kernel_launch(void* const* d_in, const int* in_sizes, int n_in,
                              void* d_out, int out_size, void* d_ws, size_t ws_size,
                              hipStream_t stream) {
    const float* x  = (const float*)d_in[0];
    const float* W1 = (const float*)d_in[1];
    const float* b1 = (const float*)d_in[2];
    const float* W2 = (const float*)d_in[3];
    const float* b2 = (const float*)d_in[4];
    float* out = (float*)d_out;

    const int npts = in_sizes[0] / 18;
    const int npairs = (npts + 1) / 2;
    const int grid = (npairs + BLOCK - 1) / BLOCK;
    mvf_kernel<<<grid, BLOCK, 0, stream>>>(x, W1, b1, W2, b2, out, npts);
}

// Round 8
// 46.223 us; speedup vs baseline: 4.4972x; 1.0579x over previous
//
#include <hip/hip_runtime.h>

// MultiVectorFieldModel: per-point routed tiny MLP (17 -> 6 -> 16), 65 models.
// fp32 weights in LDS as float4 chunks, model-minor: wlds[k4][model], k4=0..54
// over the 220-float record {W1(102), b1(6), W2(96), b2(16)}:
//   chunks 0..23  : W1 rows 0..15 (3 chunks = 2 rows per group)
//   chunk  24     : W1 row 16 (t row) j0..3
//   chunk  25     : {W1[100], W1[101], b1[0], b1[1]}
//   chunk  26     : b1[2..5]
//   chunks 27..50 : W2 row j = chunks 27+4j .. 27+4j+3 (d-major)
//   chunks 51..54 : b2
// Gather: ds_read_b128 base mid*16, chunk folds into offset: immediate.
//
// Cross-round evidence: dur ~invariant (45-60us) across layouts while all
// pipes <=30% -> latency-bound. R7 levers: (1) 1024-thread blocks (57KB LDS
// caps 2 blocks/CU either way -> 32 waves/CU), (2) early-route: the two
// float4s holding (cond,t) are issued FIRST so gathers start while the other
// 7 x loads are still in flight, (3) contiguous o[2][16] stores (R6's d-half
// split inflated WRITE 62.5->77MB via partial-line evictions).
// R3 lesson stands: never cap VGPR at 64 explicitly (spill disaster).

#define NMODELS 65
#define WPM 220
#define NCHUNK 55
#define BLOCK 1024

__global__ __launch_bounds__(BLOCK, 4) void mvf_kernel(
    const float* __restrict__ x,
    const float* __restrict__ W1,
    const float* __restrict__ b1,
    const float* __restrict__ W2,
    const float* __restrict__ b2,
    float* __restrict__ out,
    int npts)
{
    __shared__ float4 wlds[NCHUNK][NMODELS];   // 55*65*16 = 57200 B
    const int tid = threadIdx.x;

    // ---- stage weights into LDS (scalar repack into float4 chunks) ----
    float* wf = (float*)wlds;
    for (int e = tid; e < NMODELS * WPM; e += BLOCK) {
        const int m = e / WPM, k = e % WPM;
        float v;
        if (k < 102)      v = W1[m * 102 + k];
        else if (k < 108) v = b1[m * 6 + (k - 102)];
        else if (k < 204) v = W2[m * 96 + (k - 108)];
        else              v = b2[m * 16 + (k - 204)];
        wf[(k >> 2) * (NMODELS * 4) + m * 4 + (k & 3)] = v;
    }
    __syncthreads();

    const int q = blockIdx.x * BLOCK + tid;   // pair index
    const int p0 = 2 * q;                     // points p0, p0+1 (npts even)
    if (p0 >= npts) return;

    const float4* xr4 = (const float4*)(x + (long)p0 * 18);

    // ---- EARLY ROUTE: f4[4] holds (c0,t0,.,.), f4[8] holds (.,.,c1,t1).
    // Issue these first; mids are computable after waiting only on them,
    // so the weight gathers overlap the remaining 7 x-body loads.
    float xf[36];
    {
        float4 v4 = xr4[4];
        float4 v8 = xr4[8];
        xf[16] = v4.x; xf[17] = v4.y; xf[18] = v4.z; xf[19] = v4.w;
        xf[32] = v8.x; xf[33] = v8.y; xf[34] = v8.z; xf[35] = v8.w;
    }
    int mid[2];
    float tt[2];
    #pragma unroll
    for (int pt = 0; pt < 2; ++pt) {
        const float t = xf[pt * 18 + 17];
        const int c = (int)xf[pt * 18 + 16];
        int bucket = (int)floorf(t * 8.0f);
        bucket = bucket < 0 ? 0 : (bucket > 7 ? 7 : bucket);
        mid[pt] = (c == 0) ? 0 : 1 + (c - 1) * 8 + bucket;
        tt[pt] = t;
    }

    // remaining x body loads (independent, stay in flight under the gathers)
    #pragma unroll
    for (int i = 0; i < 4; ++i) {
        float4 v = xr4[i];
        xf[4 * i + 0] = v.x; xf[4 * i + 1] = v.y;
        xf[4 * i + 2] = v.z; xf[4 * i + 3] = v.w;
    }
    #pragma unroll
    for (int i = 5; i < 8; ++i) {
        float4 v = xr4[i];
        xf[4 * i + 0] = v.x; xf[4 * i + 1] = v.y;
        xf[4 * i + 2] = v.z; xf[4 * i + 3] = v.w;
    }
    #define XF(pt, i) xf[(pt) * 18 + (i)]
    #define CH(cc, pt) wlds[cc][mid[pt]]

    // ---- layer 1: h = relu(xin @ W1 + b1), xin = [data[0..15], t] ----
    float h[2][6];
    #pragma unroll
    for (int pt = 0; pt < 2; ++pt) {
        float4 c24 = CH(24, pt);
        float4 c25 = CH(25, pt);
        float4 c26 = CH(26, pt);
        const float t = tt[pt];
        h[pt][0] = fmaf(t, c24.x, c25.z);
        h[pt][1] = fmaf(t, c24.y, c25.w);
        h[pt][2] = fmaf(t, c24.z, c26.x);
        h[pt][3] = fmaf(t, c24.w, c26.y);
        h[pt][4] = fmaf(t, c25.x, c26.z);
        h[pt][5] = fmaf(t, c25.y, c26.w);
    }
    #pragma unroll
    for (int r = 0; r < 8; ++r) {
        #pragma unroll
        for (int pt = 0; pt < 2; ++pt) {
            float4 a = CH(3 * r + 0, pt);
            float4 b = CH(3 * r + 1, pt);
            float4 d = CH(3 * r + 2, pt);
            const float x0 = XF(pt, 2 * r), x1 = XF(pt, 2 * r + 1);
            h[pt][0] = fmaf(x0, a.x, h[pt][0]);
            h[pt][1] = fmaf(x0, a.y, h[pt][1]);
            h[pt][2] = fmaf(x0, a.z, h[pt][2]);
            h[pt][3] = fmaf(x0, a.w, h[pt][3]);
            h[pt][4] = fmaf(x0, b.x, h[pt][4]);
            h[pt][5] = fmaf(x0, b.y, h[pt][5]);
            h[pt][0] = fmaf(x1, b.z, h[pt][0]);
            h[pt][1] = fmaf(x1, b.w, h[pt][1]);
            h[pt][2] = fmaf(x1, d.x, h[pt][2]);
            h[pt][3] = fmaf(x1, d.y, h[pt][3]);
            h[pt][4] = fmaf(x1, d.z, h[pt][4]);
            h[pt][5] = fmaf(x1, d.w, h[pt][5]);
        }
    }
    #pragma unroll
    for (int pt = 0; pt < 2; ++pt)
        #pragma unroll
        for (int j = 0; j < 6; ++j)
            h[pt][j] = h[pt][j] > 0.0f ? h[pt][j] : 0.0f;

    // ---- layer 2: full o[2][16], contiguous stores (one 128B line/pair) ----
    float o[2][16];
    #pragma unroll
    for (int pt = 0; pt < 2; ++pt) {
        #pragma unroll
        for (int g = 0; g < 4; ++g) {
            float4 v = CH(51 + g, pt);
            o[pt][4 * g + 0] = v.x;
            o[pt][4 * g + 1] = v.y;
            o[pt][4 * g + 2] = v.z;
            o[pt][4 * g + 3] = v.w;
        }
    }
    #pragma unroll
    for (int j = 0; j < 6; ++j) {
        #pragma unroll
        for (int pt = 0; pt < 2; ++pt) {
            const float hj = h[pt][j];
            #pragma unroll
            for (int g = 0; g < 4; ++g) {
                float4 v = CH(27 + 4 * j + g, pt);
                o[pt][4 * g + 0] = fmaf(hj, v.x, o[pt][4 * g + 0]);
                o[pt][4 * g + 1] = fmaf(hj, v.y, o[pt][4 * g + 1]);
                o[pt][4 * g + 2] = fmaf(hj, v.z, o[pt][4 * g + 2]);
                o[pt][4 * g + 3] = fmaf(hj, v.w, o[pt][4 * g + 3]);
            }
        }
    }
    #undef CH
    #undef XF

    float4* orow = (float4*)(out + (long)p0 * 16);
    #pragma unroll
    for (int pt = 0; pt < 2; ++pt)
        #pragma unroll
        for (int g = 0; g < 4; ++g)
            orow[4 * pt + g] = make_float4(o[pt][4 * g], o[pt][4 * g + 1],
                                           o[pt][4 * g + 2], o[pt][4 * g + 3]);
}

extern "C" void kernel_launch(void* const* d_in, const int* in_sizes, int n_in,
                              void* d_out, int out_size, void* d_ws, size_t ws_size,
                              hipStream_t stream) {
    const float* x  = (const float*)d_in[0];
    const float* W1 = (const float*)d_in[1];
    const float* b1 = (const float*)d_in[2];
    const float* W2 = (const float*)d_in[3];
    const float* b2 = (const float*)d_in[4];
    float* out = (float*)d_out;

    const int npts = in_sizes[0] / 18;
    const int npairs = (npts + 1) / 2;
    const int grid = (npairs + BLOCK - 1) / BLOCK;
    mvf_kernel<<<grid, BLOCK, 0, stream>>>(x, W1, b1, W2, b2, out, npts);
}